// Round 4
// baseline (151.683 us; speedup 1.0000x reference)
//
#include <hip/hip_runtime.h>
#include <stdint.h>

#define KCAPS 10
#define OC    16
#define IC    256
#define HWSZ  36
#define PRIM  72
#define PD    8
#define EDIM  16

typedef short bf16x8 __attribute__((ext_vector_type(8)));
typedef float f32x4  __attribute__((ext_vector_type(4)));

// persistent prepped weights (recomputed every launch -> deterministic)
__device__ unsigned short g_whi[KCAPS * OC * IC];
__device__ unsigned short g_wlo[KCAPS * OC * IC];
__device__ float          g_wtsT[KCAPS * PRIM * EDIM * PD];   // [k][p][e][d]

// LDS (bytes):
//   phase 0-1 : xsh u32[48][132] (25344) | xsl u32[48][132] (25344) = 50688
//   post-GEMM : caps f32[10][576] flat (23040, overlays xsh) ; b_s[720] c_s[720] at 23040..28800
#define SMEM_BYTES 50688

__device__ __forceinline__ void bf_split(float v, unsigned short& hb, unsigned short& lb) {
    __bf16 h = (__bf16)v;
    hb = __builtin_bit_cast(unsigned short, h);
    __bf16 l = (__bf16)(v - (float)h);
    lb = __builtin_bit_cast(unsigned short, l);
}

__device__ __forceinline__ f32x4 mfma16(bf16x8 a, bf16x8 b, f32x4 c) {
    return __builtin_amdgcn_mfma_f32_16x16x32_bf16(a, b, c, 0, 0, 0);
}

__global__ __launch_bounds__(256)
void prep_kernel(const float* __restrict__ w, const float* __restrict__ wts) {
    int i = blockIdx.x * 256 + threadIdx.x;
    if (i < KCAPS * OC * IC) {
        unsigned short hb, lb;
        bf_split(w[i], hb, lb);
        g_whi[i] = hb;
        g_wlo[i] = lb;
    }
    if (i < KCAPS * PRIM * EDIM * PD) {          // 92160: [kp][e][d] <- [kp][d][e]
        int d = i & 7, e = (i >> 3) & 15, kp = i >> 7;
        g_wtsT[i] = wts[(size_t)kp * 128 + d * 16 + e];
    }
}

__global__ __launch_bounds__(640, 8)
void caps_one(const float* __restrict__ x, const float* __restrict__ conv_b,
              float* __restrict__ out) {
    extern __shared__ char smem[];
    uint32_t* xsh = (uint32_t*)smem;             // [48][132]
    uint32_t* xsl = xsh + 48 * 132;
    const short* xshS = (const short*)xsh;
    const short* xslS = (const short*)xsl;
    float* caps_s = (float*)smem;                // [10][576] flat, overlays xs after GEMM
    float* b_s    = (float*)smem + 5760;         // [720]
    float* c_s    = b_s + 720;                   // [720]

    const int t  = threadIdx.x;
    const int bb = blockIdx.x;
    const int k  = t >> 6;           // wave = capsule
    const int ln = t & 63;
    const int row = ln & 15;         // GEMM: w-row within tile | routing: e
    const int g   = ln >> 4;         // GEMM: k-group           | routing: pr
    const int e   = row;
    const int pr  = g;

    // ---- phase 0: stage x transposed -> bf16 hi/lo [48 hw][264 c] (rows 36-47 uninit, discarded)
    {
        const float4* x4 = (const float4*)(x + (size_t)bb * (IC * HWSZ));
        for (int task = t; task < 1152; task += 640) {   // 128 c-pairs x 9 hw-quads
            int cp = task / 9, hq = task - cp * 9;
            float4 va = x4[(2 * cp) * 9 + hq];
            float4 vb = x4[(2 * cp + 1) * 9 + hq];
            int base = (4 * hq) * 132 + cp;
            unsigned short ha, la, hb, lb;
            bf_split(va.x, ha, la); bf_split(vb.x, hb, lb);
            xsh[base]       = (uint32_t)ha | ((uint32_t)hb << 16);
            xsl[base]       = (uint32_t)la | ((uint32_t)lb << 16);
            bf_split(va.y, ha, la); bf_split(vb.y, hb, lb);
            xsh[base + 132] = (uint32_t)ha | ((uint32_t)hb << 16);
            xsl[base + 132] = (uint32_t)la | ((uint32_t)lb << 16);
            bf_split(va.z, ha, la); bf_split(vb.z, hb, lb);
            xsh[base + 264] = (uint32_t)ha | ((uint32_t)hb << 16);
            xsl[base + 264] = (uint32_t)la | ((uint32_t)lb << 16);
            bf_split(va.w, ha, la); bf_split(vb.w, hb, lb);
            xsh[base + 396] = (uint32_t)ha | ((uint32_t)hb << 16);
            xsl[base + 396] = (uint32_t)la | ((uint32_t)lb << 16);
        }
    }
    __syncthreads();

    // ---- phase 1: GEMM, wave k computes caps tile for capsule k (bf16 3-pass)
    f32x4 acc[3] = {};
    #pragma unroll 2
    for (int kt = 0; kt < 8; ++kt) {
        int woff = (k * 16 + row) * 256 + kt * 32 + g * 8;
        bf16x8 bh = *(const bf16x8*)(g_whi + woff);
        bf16x8 bl = *(const bf16x8*)(g_wlo + woff);
        #pragma unroll
        for (int nt = 0; nt < 3; ++nt) {
            int o2 = (nt * 16 + row) * 264 + kt * 32 + g * 8;
            bf16x8 ah = *(const bf16x8*)(xshS + o2);
            bf16x8 al = *(const bf16x8*)(xslS + o2);
            acc[nt] = mfma16(ah, bh, acc[nt]);
            acc[nt] = mfma16(al, bh, acc[nt]);
            acc[nt] = mfma16(ah, bl, acc[nt]);
        }
    }
    __syncthreads();                 // all xs reads done -> caps may overlay

    // ---- C-write: caps[k][flat = o*36 + hw], o = row (D-col), hw = nt*16 + g*4 + r (D-row)
    {
        float bias = conv_b[k * 16 + row];
        #pragma unroll
        for (int nt = 0; nt < 3; ++nt) {
            #pragma unroll
            for (int r = 0; r < 4; ++r) {
                int hw = nt * 16 + g * 4 + r;
                if (hw < HWSZ) caps_s[k * 576 + row * HWSZ + hw] = acc[nt][r] + bias;
            }
        }
    }
    __syncthreads();

    // ---- phase 2: u in registers. lane (pr,e) holds u[k][4*p4+pr][e], p4=0..17
    float u_reg[18];
    #pragma unroll
    for (int p4 = 0; p4 < 18; ++p4) {
        int p = 4 * p4 + pr;
        const float4* cp4 = (const float4*)(caps_s + k * 576 + p * 8);   // broadcast per 16-lane group
        float4 c0 = cp4[0], c1 = cp4[1];
        const float4* wq = (const float4*)(g_wtsT + ((size_t)(k * PRIM + p) * 16 + e) * 8);
        float4 w0 = wq[0], w1 = wq[1];
        float a = c0.x * w0.x;
        a = fmaf(c0.y, w0.y, a);
        a = fmaf(c0.z, w0.z, a);
        a = fmaf(c0.w, w0.w, a);
        a = fmaf(c1.x, w1.x, a);
        a = fmaf(c1.y, w1.y, a);
        a = fmaf(c1.z, w1.z, a);
        a = fmaf(c1.w, w1.w, a);
        u_reg[p4] = a;
    }

    // ---- phase 3: routing, register-resident
    float b_reg[18];
    float v;

    // iter 1: b=0 -> c = 0.1 exactly; no LDS, no barrier
    {
        float partial = 0.f;
        #pragma unroll
        for (int p4 = 0; p4 < 18; ++p4) partial += u_reg[p4];
        float s = partial + __shfl_xor(partial, 16);
        s += __shfl_xor(s, 32);
        s *= 0.1f;
        float sq = s * s;
        sq += __shfl_xor(sq, 1); sq += __shfl_xor(sq, 2);
        sq += __shfl_xor(sq, 4); sq += __shfl_xor(sq, 8);
        float scale = (sq / (1.f + sq)) * rsqrtf(sq + 1e-8f);
        v = s * scale;
        #pragma unroll
        for (int p4 = 0; p4 < 18; ++p4) {
            float d = u_reg[p4] * v;
            d += __shfl_xor(d, 1); d += __shfl_xor(d, 2);
            d += __shfl_xor(d, 4); d += __shfl_xor(d, 8);
            b_reg[p4] = d;           // replicated over the 16-lane e-group
        }
    }

    // iters 2,3: LDS softmax over k, everything else in-register
    #pragma unroll
    for (int it = 1; it < 3; ++it) {
        if (e == 0) {
            #pragma unroll
            for (int p4 = 0; p4 < 18; ++p4) b_s[k * PRIM + 4 * p4 + pr] = b_reg[p4];
        }
        __syncthreads();
        if (t < PRIM) {
            float bv[KCAPS];
            float m = -1e30f;
            #pragma unroll
            for (int k2 = 0; k2 < KCAPS; ++k2) { bv[k2] = b_s[k2 * PRIM + t]; m = fmaxf(m, bv[k2]); }
            float sum = 0.f;
            #pragma unroll
            for (int k2 = 0; k2 < KCAPS; ++k2) { bv[k2] = __expf(bv[k2] - m); sum += bv[k2]; }
            float inv = 1.f / sum;
            #pragma unroll
            for (int k2 = 0; k2 < KCAPS; ++k2) c_s[k2 * PRIM + t] = bv[k2] * inv;
        }
        __syncthreads();
        float partial = 0.f;
        #pragma unroll
        for (int p4 = 0; p4 < 18; ++p4)
            partial = fmaf(c_s[k * PRIM + 4 * p4 + pr], u_reg[p4], partial);
        float s = partial + __shfl_xor(partial, 16);
        s += __shfl_xor(s, 32);
        float sq = s * s;
        sq += __shfl_xor(sq, 1); sq += __shfl_xor(sq, 2);
        sq += __shfl_xor(sq, 4); sq += __shfl_xor(sq, 8);
        float scale = (sq / (1.f + sq)) * rsqrtf(sq + 1e-8f);
        v = s * scale;
        if (it < 2) {
            #pragma unroll
            for (int p4 = 0; p4 < 18; ++p4) {
                float d = u_reg[p4] * v;
                d += __shfl_xor(d, 1); d += __shfl_xor(d, 2);
                d += __shfl_xor(d, 4); d += __shfl_xor(d, 8);
                b_reg[p4] += d;
            }
        }
    }

    if (ln < 16) out[(size_t)bb * (KCAPS * EDIM) + k * 16 + ln] = v;
}

extern "C" void kernel_launch(void* const* d_in, const int* in_sizes, int n_in,
                              void* d_out, int out_size, void* d_ws, size_t ws_size,
                              hipStream_t stream) {
    const float* x  = (const float*)d_in[0];
    const float* cw = (const float*)d_in[1];
    const float* cb = (const float*)d_in[2];
    const float* wt = (const float*)d_in[3];
    float* out = (float*)d_out;
    const int B = in_sizes[0] / (IC * HWSZ);   // 2048

    hipLaunchKernelGGL(prep_kernel, dim3((KCAPS * PRIM * EDIM * PD + 255) / 256), dim3(256),
                       0, stream, cw, wt);

    hipFuncSetAttribute(reinterpret_cast<const void*>(&caps_one),
                        hipFuncAttributeMaxDynamicSharedMemorySize, SMEM_BYTES);
    hipLaunchKernelGGL(caps_one, dim3(B), dim3(640), SMEM_BYTES, stream, x, cb, out);
}

// Round 5
// 138.866 us; speedup vs baseline: 1.0923x; 1.0923x over previous
//
#include <hip/hip_runtime.h>
#include <stdint.h>

#define KCAPS 10
#define OC    16
#define IC    256
#define HWSZ  36
#define PRIM  72
#define PD    8
#define EDIM  16

typedef short bf16x8 __attribute__((ext_vector_type(8)));
typedef float f32x4  __attribute__((ext_vector_type(4)));

// persistent prepped weights (recomputed every launch -> deterministic)
__device__ unsigned short g_whi[KCAPS * OC * IC];
__device__ unsigned short g_wlo[KCAPS * OC * IC];
__device__ float          g_wtsT[KCAPS * PRIM * EDIM * PD];   // [k][p][e][d]

// LDS float map (74880 B total):
//   [0, 9504)      xs: xsh u32[36][132] then xsl u32[36][132] (bytes [0,38016); GEMM frag
//                  reads for discarded D-rows 36..47 run past each half -> garbage, in-bounds)
//   [0, 12960)     u_s f32[720][18]  (overlays xs after post-GEMM barrier)
//   [12960, 18720) caps f32[10][576] (phase C-write..P2)
//   [12960, ...)   b_s[720] c_s[720] overlay caps during routing (barrier-protected)
#define SMEM_BYTES 74880
#define CAPS_F     12960

__device__ __forceinline__ void bf_split(float v, unsigned short& hb, unsigned short& lb) {
    __bf16 h = (__bf16)v;
    hb = __builtin_bit_cast(unsigned short, h);
    __bf16 l = (__bf16)(v - (float)h);
    lb = __builtin_bit_cast(unsigned short, l);
}

__device__ __forceinline__ f32x4 mfma16(bf16x8 a, bf16x8 b, f32x4 c) {
    return __builtin_amdgcn_mfma_f32_16x16x32_bf16(a, b, c, 0, 0, 0);
}

__global__ __launch_bounds__(256)
void prep_kernel(const float* __restrict__ w, const float* __restrict__ wts) {
    int i = blockIdx.x * 256 + threadIdx.x;
    if (i < KCAPS * OC * IC) {
        unsigned short hb, lb;
        bf_split(w[i], hb, lb);
        g_whi[i] = hb;
        g_wlo[i] = lb;
    }
    if (i < KCAPS * PRIM * EDIM * PD) {           // 92160: [kp][e][d] <- [kp][d][e]
        int d = i & 7, e = (i >> 3) & 15, kp = i >> 7;
        g_wtsT[i] = wts[(size_t)kp * 128 + d * 16 + e];
    }
}

__global__ __launch_bounds__(640, 5)
void caps_one(const float* __restrict__ x, const float* __restrict__ conv_b,
              float* __restrict__ out) {
    extern __shared__ char smem[];
    uint32_t* xsh = (uint32_t*)smem;              // [36][132] (+garbage margin)
    uint32_t* xsl = xsh + 36 * 132;
    const short* xshS = (const short*)xsh;
    const short* xslS = (const short*)xsl;
    float* u_s    = (float*)smem;                 // [720][18], overlays xs post-GEMM
    float* caps_s = (float*)smem + CAPS_F;        // [10][576]
    float* b_s    = (float*)smem + CAPS_F;        // routing overlays caps
    float* c_s    = b_s + 720;

    const int t  = threadIdx.x;
    const int bb = blockIdx.x;
    const int k  = t >> 6;            // wave = capsule
    const int ln = t & 63;
    const int row = ln & 15;          // GEMM: tile row | routing: e
    const int g   = ln >> 4;          // GEMM: k-group  | routing: pr
    const int e   = row;
    const int pr  = g;

    // ---- phase 0: stage x transposed -> bf16 hi/lo [36 hw][264 c]
    {
        const float4* x4 = (const float4*)(x + (size_t)bb * (IC * HWSZ));
        for (int task = t; task < 1152; task += 640) {   // 128 c-pairs x 9 hw-quads
            int cp = task / 9, hq = task - cp * 9;
            float4 va = x4[(2 * cp) * 9 + hq];
            float4 vb = x4[(2 * cp + 1) * 9 + hq];
            int base = (4 * hq) * 132 + cp;
            unsigned short ha, la, hb, lb;
            bf_split(va.x, ha, la); bf_split(vb.x, hb, lb);
            xsh[base]       = (uint32_t)ha | ((uint32_t)hb << 16);
            xsl[base]       = (uint32_t)la | ((uint32_t)lb << 16);
            bf_split(va.y, ha, la); bf_split(vb.y, hb, lb);
            xsh[base + 132] = (uint32_t)ha | ((uint32_t)hb << 16);
            xsl[base + 132] = (uint32_t)la | ((uint32_t)lb << 16);
            bf_split(va.z, ha, la); bf_split(vb.z, hb, lb);
            xsh[base + 264] = (uint32_t)ha | ((uint32_t)hb << 16);
            xsl[base + 264] = (uint32_t)la | ((uint32_t)lb << 16);
            bf_split(va.w, ha, la); bf_split(vb.w, hb, lb);
            xsh[base + 396] = (uint32_t)ha | ((uint32_t)hb << 16);
            xsl[base + 396] = (uint32_t)la | ((uint32_t)lb << 16);
        }
    }
    __syncthreads();

    // ---- phase 1: GEMM, wave k computes its own 16x36 caps tile (bf16 3-pass)
    f32x4 acc[3] = {};
    #pragma unroll 2
    for (int kt = 0; kt < 8; ++kt) {
        int woff = (k * 16 + row) * 256 + kt * 32 + g * 8;
        bf16x8 bh = *(const bf16x8*)(g_whi + woff);
        bf16x8 bl = *(const bf16x8*)(g_wlo + woff);
        #pragma unroll
        for (int nt = 0; nt < 3; ++nt) {
            int o2 = (nt * 16 + row) * 264 + kt * 32 + g * 8;
            bf16x8 ah = *(const bf16x8*)(xshS + o2);
            bf16x8 al = *(const bf16x8*)(xslS + o2);
            acc[nt] = mfma16(ah, bh, acc[nt]);
            acc[nt] = mfma16(al, bh, acc[nt]);
            acc[nt] = mfma16(ah, bl, acc[nt]);
        }
    }

    // ---- C-write: caps[k][o*36+hw]; caps region disjoint from xs -> no barrier needed first
    {
        float bias = conv_b[k * 16 + row];
        #pragma unroll
        for (int nt = 0; nt < 3; ++nt) {
            #pragma unroll
            for (int r = 0; r < 4; ++r) {
                int hw = nt * 16 + g * 4 + r;
                if (hw < HWSZ) caps_s[k * 576 + row * HWSZ + hw] = acc[nt][r] + bias;
            }
        }
    }
    __syncthreads();    // all xs reads done -> u_s may overlay xs

    // ---- phase 2: u[p][e] to LDS; lane (pr,e) computes p = 4*p4+pr. part1 = iter-1 s-partial
    float part1 = 0.f;
    #pragma unroll
    for (int p4 = 0; p4 < 18; ++p4) {
        int p = 4 * p4 + pr;
        const float4* cp4 = (const float4*)(caps_s + k * 576 + p * 8);   // broadcast over e-group
        float4 c0 = cp4[0], c1 = cp4[1];
        const float4* wq = (const float4*)(g_wtsT + ((size_t)(k * PRIM + p) * 16 + e) * 8);
        float4 w0 = wq[0], w1 = wq[1];
        float a = c0.x * w0.x;
        a = fmaf(c0.y, w0.y, a);
        a = fmaf(c0.z, w0.z, a);
        a = fmaf(c0.w, w0.w, a);
        a = fmaf(c1.x, w1.x, a);
        a = fmaf(c1.y, w1.y, a);
        a = fmaf(c1.z, w1.z, a);
        a = fmaf(c1.w, w1.w, a);
        u_s[(k * PRIM + p) * 18 + e] = a;
        part1 += a;
    }

    // ---- phase 3 iter 1: b=0 -> c=0.1 exactly; pure shuffles, no barrier
    float b_reg[18];
    float v;
    {
        float s = part1 + __shfl_xor(part1, 16);
        s += __shfl_xor(s, 32);
        s *= 0.1f;
        float sq = s * s;
        sq += __shfl_xor(sq, 1); sq += __shfl_xor(sq, 2);
        sq += __shfl_xor(sq, 4); sq += __shfl_xor(sq, 8);
        float scale = (sq / (1.f + sq)) * rsqrtf(sq + 1e-8f);
        v = s * scale;
        #pragma unroll
        for (int p4 = 0; p4 < 18; ++p4) {
            float d = u_s[(k * PRIM + 4 * p4 + pr) * 18 + e] * v;
            d += __shfl_xor(d, 1); d += __shfl_xor(d, 2);
            d += __shfl_xor(d, 4); d += __shfl_xor(d, 8);
            b_reg[p4] = d;            // replicated across e-group
        }
    }

    // ---- iters 2,3: LDS softmax over k; s-sum/squash/agreement via shuffles
    #pragma unroll
    for (int it = 1; it < 3; ++it) {
        __syncthreads();              // (a) protect caps overlay (it=1) / c_s reuse (it=2)
        if (e == 0) {
            #pragma unroll
            for (int p4 = 0; p4 < 18; ++p4) b_s[k * PRIM + 4 * p4 + pr] = b_reg[p4];
        }
        __syncthreads();              // (b) b_s visible
        if (t < PRIM) {
            float bv[KCAPS];
            float m = -1e30f;
            #pragma unroll
            for (int k2 = 0; k2 < KCAPS; ++k2) { bv[k2] = b_s[k2 * PRIM + t]; m = fmaxf(m, bv[k2]); }
            float sum = 0.f;
            #pragma unroll
            for (int k2 = 0; k2 < KCAPS; ++k2) { bv[k2] = __expf(bv[k2] - m); sum += bv[k2]; }
            float inv = 1.f / sum;
            #pragma unroll
            for (int k2 = 0; k2 < KCAPS; ++k2) c_s[k2 * PRIM + t] = bv[k2] * inv;
        }
        __syncthreads();              // (c) c_s visible
        float partial = 0.f;
        #pragma unroll
        for (int p4 = 0; p4 < 18; ++p4) {
            int p = 4 * p4 + pr;
            partial = fmaf(c_s[k * PRIM + p], u_s[(k * PRIM + p) * 18 + e], partial);
        }
        float s = partial + __shfl_xor(partial, 16);
        s += __shfl_xor(s, 32);
        float sq = s * s;
        sq += __shfl_xor(sq, 1); sq += __shfl_xor(sq, 2);
        sq += __shfl_xor(sq, 4); sq += __shfl_xor(sq, 8);
        float scale = (sq / (1.f + sq)) * rsqrtf(sq + 1e-8f);
        v = s * scale;
        if (it < 2) {                 // agreement update (skip after final iter)
            #pragma unroll
            for (int p4 = 0; p4 < 18; ++p4) {
                float d = u_s[(k * PRIM + 4 * p4 + pr) * 18 + e] * v;
                d += __shfl_xor(d, 1); d += __shfl_xor(d, 2);
                d += __shfl_xor(d, 4); d += __shfl_xor(d, 8);
                b_reg[p4] += d;
            }
        }
    }

    if (ln < 16) out[(size_t)bb * (KCAPS * EDIM) + k * 16 + ln] = v;
}

extern "C" void kernel_launch(void* const* d_in, const int* in_sizes, int n_in,
                              void* d_out, int out_size, void* d_ws, size_t ws_size,
                              hipStream_t stream) {
    const float* x  = (const float*)d_in[0];
    const float* cw = (const float*)d_in[1];
    const float* cb = (const float*)d_in[2];
    const float* wt = (const float*)d_in[3];
    float* out = (float*)d_out;
    const int B = in_sizes[0] / (IC * HWSZ);   // 2048

    hipLaunchKernelGGL(prep_kernel, dim3((KCAPS * PRIM * EDIM * PD + 255) / 256), dim3(256),
                       0, stream, cw, wt);

    hipFuncSetAttribute(reinterpret_cast<const void*>(&caps_one),
                        hipFuncAttributeMaxDynamicSharedMemorySize, SMEM_BYTES);
    hipLaunchKernelGGL(caps_one, dim3(B), dim3(640), SMEM_BYTES, stream, x, cb, out);
}